// Round 1
// baseline (206.869 us; speedup 1.0000x reference)
//
#include <hip/hip_runtime.h>
#include <hip/hip_bf16.h>

// TRANSNET on MI355X — round 7: global_load_lds staging (direct HBM->LDS,
// XOR-swizzled 128B rows), 4 blocks/CU, XCD-aware remap.
// Per review: GEMM M=256(L) x N=112(Fpad) x K=192 via mfma_f32_16x16x32_bf16
// in two N-passes; B-fragments pre-packed in global (L2-hot); LDS = emb only.
// (Round 8 resubmission: identical source — prior bench container failed;
// re-establishing baseline + counters before next change.)

#define C_V 50000
#define C_D 64
#define C_F 100
#define C_K 3
#define C_L 256
#define C_R 10
#define C_ID 32
#define C_B 128

typedef unsigned int u32;
typedef unsigned short u16;
typedef __attribute__((ext_vector_type(8))) short bf16x8;
typedef __attribute__((ext_vector_type(4))) float f32x4;

__device__ __forceinline__ float bf2f(u16 h) { union {u32 u; float f;} v; v.u = ((u32)h) << 16; return v.f; }
__device__ __forceinline__ u16 f2bf(float f) {
    union {float f; u32 u;} v; v.f = f;
    u32 u = v.u;
    return (u16)((u + 0x7fffu + ((u >> 16) & 1u)) >> 16);  // RNE
}
__device__ __forceinline__ float ldf(const void* p, int idx, int isf) {
    return isf ? ((const float*)p)[idx] : bf2f(((const u16*)p)[idx]);
}
__device__ __forceinline__ void stf(void* p, int idx, float v, int isf) {
    if (isf) ((float*)p)[idx] = v; else ((u16*)p)[idx] = f2bf(v);
}
// Per-wave dtype probe: bf16 halves of N(0,0.1) values have exponent field in
// [0x70,0x7F]; f32 low-16 mantissa bits hit that window ~1/16 of the time.
__device__ __forceinline__ int detect_isf(const u32* __restrict__ ue, int lane) {
    u32 w = ue[lane];
    u32 e = (w >> 7) & 0xFFu;
    int hit = (e >= 0x70u && e <= 0x7Fu);
    unsigned long long m = __ballot(hit);
    return (__popcll(m) >= 32) ? 0 : 1;
}
// async global->LDS, 16B per lane; lds base must be wave-uniform.
__device__ __forceinline__ void gl_lds16(const void* g, void* l) {
    __builtin_amdgcn_global_load_lds(
        (const __attribute__((address_space(1))) void*)g,
        (__attribute__((address_space(3))) void*)l, 16, 0, 0);
}

// ---------------------------------------------------------------------------
// K0: pre-pack B fragments: [set(3)][c(6)][nt(7)][lane(64)][j(8)] bf16 —
// exactly the per-lane 16B the GEMM loads. f>=100 zero-padded.
// ---------------------------------------------------------------------------
__global__ __launch_bounds__(256) void prep_bfrags(
    const void* __restrict__ cu_Wc, const void* __restrict__ ci_Wc,
    const void* __restrict__ tc_Wc, const u32* __restrict__ ue,
    u16* __restrict__ wsB)
{
    int tid = threadIdx.x;
    int isf = detect_isf(ue, tid & 63);
    int id = blockIdx.x * 256 + tid;           // 3*6*7*64 = 8064 total
    if (id >= 3 * 6 * 7 * 64) return;
    int s    = id / 2688;
    int rem  = id % 2688;
    int c    = rem / 448;
    int rem2 = rem % 448;
    int nt   = rem2 / 64;
    int lane = rem2 % 64;
    int f    = nt * 16 + (lane & 15);
    int quad = lane >> 4;
    const void* W = (s == 0) ? cu_Wc : (s == 1) ? ci_Wc : tc_Wc;
    u16 out[8];
    #pragma unroll
    for (int j = 0; j < 8; ++j) {
        int kdim = c * 32 + quad * 8 + j;
        int tap = kdim >> 6, d = kdim & 63;
        float v = (f < C_F) ? ldf(W, (f * C_D + d) * C_K + tap, isf) : 0.f;
        out[j] = f2bf(v);
    }
    *reinterpret_cast<uint4*>(wsB + id * 8) = *reinterpret_cast<const uint4*>(out);
}

// ---------------------------------------------------------------------------
// K1: one block (4 waves) per review (2688).
// embS: 258 rows x 64 bf16 (128 B), XOR-chunk swizzle: 16B chunk c of row r
// lives in slot c^(r&7). Staged via global_load_lds (8 rows/instr/wave).
// LDS total 34.6 KB -> 4 blocks/CU.
// ---------------------------------------------------------------------------
__global__ __launch_bounds__(256, 4) void cnn_mfma(
    const int* __restrict__ user_reviews, const int* __restrict__ item_reviews,
    const int* __restrict__ uids, const int* __restrict__ iids,
    const int* __restrict__ user2item, const int* __restrict__ item2user,
    const int* __restrict__ rand_reviews,
    const void* __restrict__ user_emb, const void* __restrict__ item_emb,
    const void* __restrict__ te_emb,
    const void* __restrict__ cu_bc, const void* __restrict__ cu_Wl, const void* __restrict__ cu_bl,
    const void* __restrict__ ci_bc, const void* __restrict__ ci_Wl, const void* __restrict__ ci_bl,
    const void* __restrict__ tc_bc, const void* __restrict__ tc_Wl, const void* __restrict__ tc_bl,
    const u16* __restrict__ wsB,
    float* __restrict__ ws_cat, void* __restrict__ d_out)
{
    __shared__ __align__(16) char smem[258 * 128 + 1600];
    u16*   embS  = (u16*)smem;                  // [258][64] bf16, swizzled
    float* poolS = (float*)(smem + 258 * 128);  // [100][4]
    float* partS = (float*)smem;                // reused after GEMM

    const int tid = threadIdx.x;
    // XCD-aware remap: round-robin dispatch -> contiguous review range per XCD.
    const int idx = (blockIdx.x & 7) * 336 + (blockIdx.x >> 3);
    const int lane = tid & 63, wave = tid >> 6;
    const int isf = detect_isf((const u32*)user_emb, lane);

    const int* toks;
    const void* emb;
    int set;
    const void *bc, *Wl, *bl;

    if (idx < C_B * C_R) {                         // user reviews
        toks = user_reviews + idx * C_L;
        emb = user_emb; set = 0;
        bc = cu_bc; Wl = cu_Wl; bl = cu_bl;
    } else if (idx < 2 * C_B * C_R) {              // item reviews
        int j = idx - C_B * C_R;
        toks = item_reviews + j * C_L;
        emb = item_emb; set = 1;
        bc = ci_bc; Wl = ci_Wl; bl = ci_bl;
    } else {                                       // target review (selected)
        int b = idx - 2 * C_B * C_R;
        const int* t_ = rand_reviews + b * C_L;
        int iid = iids[b];
        int uid = uids[b];
        int fu = -1, fi = -1;
        for (int r = C_R - 1; r >= 0; --r) {       // first match (argmax of bool)
            if (user2item[b * C_R + r] == iid) fu = r;
            if (item2user[b * C_R + r] == uid) fi = r;
        }
        if (fu >= 0)      t_ = user_reviews + (b * C_R + fu) * C_L;
        else if (fi >= 0) t_ = item_reviews + (b * C_R + fi) * C_L;
        toks = t_;
        emb = te_emb; set = 2;
        bc = tc_bc; Wl = tc_Wl; bl = tc_bl;
    }

    // zero pad rows 0 (pos -1) and 257 (pos 256): 32 u32 each
    if (tid < 32)            ((u32*)embS)[tid] = 0u;
    else if (tid < 64)       ((u32*)embS)[257 * 32 + (tid - 32)] = 0u;

    // ---- stage embedding rows ----
    if (!isf) {
        // bf16 fast path: wave w stages rows [w*64, w*64+64) via 8
        // global_load_lds dwordx4: instr i covers 8 rows; lane -> row
        // w*64+i*8+(lane>>3), chunk slot lane&7, source chunk swizzled.
        int tok64 = toks[wave * 64 + lane];
        const u16* ebp = (const u16*)emb;
        #pragma unroll
        for (int i = 0; i < 8; ++i) {
            int sub = lane >> 3;                       // row within batch
            int token = __shfl(tok64, i * 8 + sub);
            int row_lds = wave * 64 + i * 8 + sub + 1;
            int schunk = (lane & 7) ^ (row_lds & 7);
            const void* g = ebp + (size_t)token * C_D + schunk * 8;
            u16* ldsbase = embS + (size_t)(wave * 64 + i * 8 + 1) * 64; // uniform
            gl_lds16(g, ldsbase);
        }
    } else {
        // f32 fallback: per-thread row, convert, store with same swizzle
        int token = toks[tid];
        int rw = (tid + 1) & 7;
        u16* dst = embS + (size_t)(tid + 1) * 64;
        const float4* srow = reinterpret_cast<const float4*>(
            (const float*)emb + (size_t)token * C_D);
        #pragma unroll
        for (int c = 0; c < 8; ++c) {
            float4 a = srow[2 * c];
            float4 b = srow[2 * c + 1];
            u16 t[8] = {f2bf(a.x), f2bf(a.y), f2bf(a.z), f2bf(a.w),
                        f2bf(b.x), f2bf(b.y), f2bf(b.z), f2bf(b.w)};
            *reinterpret_cast<uint4*>(dst + (c ^ rw) * 8) =
                *reinterpret_cast<const uint4*>(t);
        }
    }
    __syncthreads();

    const int quad = lane >> 4, mcol = lane & 15;
    const int mbase = wave * 64;
    const u16* BfG = wsB + set * 21504;   // this set's fragments

    // ---- pass 0: nt 0..3 (f 0..63) ----
    {
        f32x4 acc[4][4];
        #pragma unroll
        for (int mt = 0; mt < 4; ++mt)
            #pragma unroll
            for (int nt = 0; nt < 4; ++nt) acc[mt][nt] = (f32x4){0.f,0.f,0.f,0.f};
        #pragma unroll
        for (int c = 0; c < 6; ++c) {
            const int tap = c >> 1, dh = c & 1;
            // swizzled chunk slot: uniform over mt (mt*16 % 8 == 0)
            const int schunk = (dh * 4 + quad) ^ ((mcol + tap) & 7);
            bf16x8 bfr[4];
            #pragma unroll
            for (int nt = 0; nt < 4; ++nt)
                bfr[nt] = *reinterpret_cast<const bf16x8*>(BfG + ((c * 7 + nt) * 64 + lane) * 8);
            bf16x8 afr[4];
            #pragma unroll
            for (int mt = 0; mt < 4; ++mt) {
                int row = mbase + mt * 16 + mcol + tap;   // lds row (= pos + tap, pad-shifted)
                afr[mt] = *reinterpret_cast<const bf16x8*>(embS + row * 64 + schunk * 8);
            }
            #pragma unroll
            for (int mt = 0; mt < 4; ++mt)
                #pragma unroll
                for (int nt = 0; nt < 4; ++nt)
                    acc[mt][nt] = __builtin_amdgcn_mfma_f32_16x16x32_bf16(
                        afr[mt], bfr[nt], acc[mt][nt], 0, 0, 0);
        }
        #pragma unroll
        for (int nt = 0; nt < 4; ++nt) {
            float mv = -1e30f;
            #pragma unroll
            for (int mt = 0; mt < 4; ++mt)
                mv = fmaxf(mv, fmaxf(fmaxf(acc[mt][nt].x, acc[mt][nt].y),
                                     fmaxf(acc[mt][nt].z, acc[mt][nt].w)));
            mv = fmaxf(mv, __shfl_xor(mv, 16));
            mv = fmaxf(mv, __shfl_xor(mv, 32));
            if (quad == 0) poolS[(nt * 16 + mcol) * 4 + wave] = mv;   // f<=63<100
        }
    }
    // ---- pass 1: nt 4..6 (f 64..111, pad-zeros beyond 99) ----
    {
        f32x4 acc[4][3];
        #pragma unroll
        for (int mt = 0; mt < 4; ++mt)
            #pragma unroll
            for (int nt = 0; nt < 3; ++nt) acc[mt][nt] = (f32x4){0.f,0.f,0.f,0.f};
        #pragma unroll
        for (int c = 0; c < 6; ++c) {
            const int tap = c >> 1, dh = c & 1;
            const int schunk = (dh * 4 + quad) ^ ((mcol + tap) & 7);
            bf16x8 bfr[3];
            #pragma unroll
            for (int nt = 0; nt < 3; ++nt)
                bfr[nt] = *reinterpret_cast<const bf16x8*>(BfG + ((c * 7 + 4 + nt) * 64 + lane) * 8);
            bf16x8 afr[4];
            #pragma unroll
            for (int mt = 0; mt < 4; ++mt) {
                int row = mbase + mt * 16 + mcol + tap;
                afr[mt] = *reinterpret_cast<const bf16x8*>(embS + row * 64 + schunk * 8);
            }
            #pragma unroll
            for (int mt = 0; mt < 4; ++mt)
                #pragma unroll
                for (int nt = 0; nt < 3; ++nt)
                    acc[mt][nt] = __builtin_amdgcn_mfma_f32_16x16x32_bf16(
                        afr[mt], bfr[nt], acc[mt][nt], 0, 0, 0);
        }
        #pragma unroll
        for (int nt = 0; nt < 3; ++nt) {
            float mv = -1e30f;
            #pragma unroll
            for (int mt = 0; mt < 4; ++mt)
                mv = fmaxf(mv, fmaxf(fmaxf(acc[mt][nt].x, acc[mt][nt].y),
                                     fmaxf(acc[mt][nt].z, acc[mt][nt].w)));
            mv = fmaxf(mv, __shfl_xor(mv, 16));
            mv = fmaxf(mv, __shfl_xor(mv, 32));
            int f = (4 + nt) * 16 + mcol;
            if (quad == 0 && f < C_F) poolS[f * 4 + wave] = mv;
        }
    }
    __syncthreads();

    // cross-wave max + bias + relu -> poolS[f*4]
    if (tid < C_F) {
        float m4 = fmaxf(fmaxf(poolS[tid * 4 + 0], poolS[tid * 4 + 1]),
                         fmaxf(poolS[tid * 4 + 2], poolS[tid * 4 + 3]));
        poolS[tid * 4] = fmaxf(m4 + ldf(bc, tid, isf), 0.f);
    }
    __syncthreads();

    // wide linear F->ID: 8 threads per output, 12-13 f each
    {
        int o = tid >> 3, seg = tid & 7;
        int f0 = (seg < 4) ? seg * 13 : 52 + (seg - 4) * 12;
        int cnt = (seg < 4) ? 13 : 12;
        float acc = 0.f;
        for (int q = 0; q < cnt; ++q) {
            int f = f0 + q;
            acc += poolS[f * 4] * ldf(Wl, o * C_F + f, isf);
        }
        partS[o * 8 + seg] = acc;
    }
    __syncthreads();
    if (tid < C_ID) {
        float s = ldf(bl, tid, isf);
        #pragma unroll
        for (int q = 0; q < 8; ++q) s += partS[tid * 8 + q];
        float v = tanhf(s);
        if (idx < C_B * C_R) {
            int b = idx / C_R, r = idx % C_R;
            ws_cat[b * 640 + r * C_ID + tid] = v;
        } else if (idx < 2 * C_B * C_R) {
            int j = idx - C_B * C_R;
            int b = j / C_R, r = j % C_R;
            ws_cat[b * 640 + 320 + r * C_ID + tid] = v;
        } else {
            int b = idx - 2 * C_B * C_R;
            stf(d_out, C_B * C_ID + b * C_ID + tid, v, isf);   // tl after src
        }
    }
}

// ---------------------------------------------------------------------------
// K2: src head: h = tanh(cat @ W1^T + b1); src = tanh(h @ W2^T + b2).
// ---------------------------------------------------------------------------
__global__ __launch_bounds__(256) void head_kernel(
    const float* __restrict__ ws_cat,
    const void* __restrict__ W1, const void* __restrict__ b1,
    const void* __restrict__ W2, const void* __restrict__ b2,
    const u32* __restrict__ ue, void* __restrict__ d_out)
{
    __shared__ float part[C_ID][8];
    __shared__ float h_s[C_ID];
    int b = blockIdx.x;
    int tid = threadIdx.x;
    int isf = detect_isf(ue, tid & 63);
    int o = tid >> 3, seg = tid & 7;
    const float* cat = ws_cat + b * 640;
    float acc = 0.f;
    int j0 = seg * 80;
    for (int j = j0; j < j0 + 80; ++j) acc += cat[j] * ldf(W1, o * 640 + j, isf);
    part[o][seg] = acc;
    __syncthreads();
    if (tid < C_ID) {
        float s = ldf(b1, tid, isf);
        #pragma unroll
        for (int q = 0; q < 8; ++q) s += part[tid][q];
        h_s[tid] = tanhf(s);
    }
    __syncthreads();
    if (tid < C_ID) {
        float s = ldf(b2, tid, isf);
        #pragma unroll
        for (int i = 0; i < C_ID; ++i) s += h_s[i] * ldf(W2, tid * C_ID + i, isf);
        stf(d_out, b * C_ID + tid, tanhf(s), isf);
    }
}

extern "C" void kernel_launch(void* const* d_in, const int* in_sizes, int n_in,
                              void* d_out, int out_size, void* d_ws, size_t ws_size,
                              hipStream_t stream)
{
    const int* user_reviews = (const int*)d_in[0];
    const int* item_reviews = (const int*)d_in[1];
    const int* uids         = (const int*)d_in[2];
    const int* iids         = (const int*)d_in[3];
    const int* user2item    = (const int*)d_in[4];
    const int* item2user    = (const int*)d_in[5];
    const int* rand_reviews = (const int*)d_in[6];
    const void* user_emb = d_in[7];
    const void* item_emb = d_in[8];
    const void* cu_Wc = d_in[9];
    const void* cu_bc = d_in[10];
    const void* cu_Wl = d_in[11];
    const void* cu_bl = d_in[12];
    const void* ci_Wc = d_in[13];
    const void* ci_bc = d_in[14];
    const void* ci_Wl = d_in[15];
    const void* ci_bl = d_in[16];
    const void* t_W1  = d_in[17];
    const void* t_b1  = d_in[18];
    const void* t_W2  = d_in[19];
    const void* t_b2  = d_in[20];
    // d_in[21..23]: fs_* — outputs unused
    const void* te_emb = d_in[24];
    const void* tc_Wc  = d_in[25];
    const void* tc_bc  = d_in[26];
    const void* tc_Wl  = d_in[27];
    const void* tc_bl  = d_in[28];
    // d_in[29..31]: ft_* — unused

    u16*   ws_B   = (u16*)d_ws;                                 // 129024 B
    float* ws_cat = (float*)((char*)d_ws + 129536);             // 128*640 f32

    prep_bfrags<<<32, 256, 0, stream>>>(cu_Wc, ci_Wc, tc_Wc,
                                        (const u32*)user_emb, ws_B);

    cnn_mfma<<<2 * C_B * C_R + C_B, 256, 0, stream>>>(
        user_reviews, item_reviews, uids, iids, user2item, item2user, rand_reviews,
        user_emb, item_emb, te_emb,
        cu_bc, cu_Wl, cu_bl, ci_bc, ci_Wl, ci_bl, tc_bc, tc_Wl, tc_bl,
        ws_B, ws_cat, d_out);

    head_kernel<<<C_B, 256, 0, stream>>>(ws_cat, t_W1, t_b1, t_W2, t_b2,
                                         (const u32*)user_emb, d_out);
}